// Round 6
// baseline (231.843 us; speedup 1.0000x reference)
//
#include <hip/hip_runtime.h>
#include <hip/hip_bf16.h>
#include <stdint.h>

#define B 4
#define S 2048
#define D 1024
#define H 16
#define DH 64
#define M_TOT (B*S)
#define BH (B*H)

typedef unsigned short u16;
typedef unsigned int u32;
typedef __attribute__((ext_vector_type(4))) float f32x4;
typedef __attribute__((ext_vector_type(16))) float f32x16;
typedef __attribute__((ext_vector_type(8))) short bf16x8;
typedef __attribute__((ext_vector_type(2))) unsigned int u32x2;

typedef const __attribute__((address_space(1))) unsigned int* gp_t;
typedef __attribute__((address_space(3))) unsigned int* lp_t;

__device__ __forceinline__ void gload_lds16(const void* g, void* l) {
    __builtin_amdgcn_global_load_lds((gp_t)g, (lp_t)l, 16, 0, 0);
}

__device__ __forceinline__ float bf2f(u16 u) {
    u32 t = ((u32)u) << 16;
    float f; __builtin_memcpy(&f, &t, 4); return f;
}
__device__ __forceinline__ u16 f2bf(float f) {   // RTNE
    u32 u; __builtin_memcpy(&u, &f, 4);
    u += 0x7fffu + ((u >> 16) & 1u);
    return (u16)(u >> 16);
}
__device__ __forceinline__ u32 packbf(float lo, float hi_) {
    __hip_bfloat162 h = __float22bfloat162_rn(float2{lo, hi_});
    u32 r; __builtin_memcpy(&r, &h, 4); return r;
}

__device__ __forceinline__ float exp2_fast(float x) { return __builtin_amdgcn_exp2f(x); }

#if __has_builtin(__builtin_amdgcn_permlane32_swap)
__device__ __forceinline__ void plswap(u32& a, u32& bb) {
    u32x2 r = __builtin_amdgcn_permlane32_swap(a, bb, false, false);
    a = r.x; bb = r.y;
}
#else
__device__ __forceinline__ void plswap(u32& a, u32& bb) {
    int hi = (threadIdx.x >> 5) & 1;
    u32 ra = (u32)__shfl_xor((int)a, 32);
    u32 rb = (u32)__shfl_xor((int)bb, 32);
    u32 na = hi ? rb : a;
    u32 nb = hi ? bb : ra;
    a = na; bb = nb;
}
#endif

// ---------------- fp32 -> bf16 cast (vectorized x8) ----------------
__global__ __launch_bounds__(256)
void cvt_kernel(const float* __restrict__ src, u16* __restrict__ dst, int n) {
    int i = (blockIdx.x * 256 + threadIdx.x) * 8;
    if (i >= n) return;
    float4 a = *(const float4*)(src + i);
    float4 b = *(const float4*)(src + i + 4);
    union { u16 u[8]; bf16x8 v; } o;
    o.u[0] = f2bf(a.x); o.u[1] = f2bf(a.y); o.u[2] = f2bf(a.z); o.u[3] = f2bf(a.w);
    o.u[4] = f2bf(b.x); o.u[5] = f2bf(b.y); o.u[6] = f2bf(b.z); o.u[7] = f2bf(b.w);
    *(bf16x8*)(dst + i) = o.v;
}

// ---------------- bf16 MFMA GEMM (m97 structure) ----------------
// DO_ROPE: fuse rotary embedding into the epilogue (z=0 -> Q with cs2 scale,
// z=1 -> K unscaled). A wave's j-fragments span exactly one 64-wide head, so
// the rope pair (d, d+32) is acc[i][jh] / acc[i][jh+2] -- in-thread.
template<int WRITE_BF16, int DO_ROPE>
__global__ __launch_bounds__(256)
void gemm_mfma(const u16* __restrict__ X,
               const u16* __restrict__ W0, const u16* __restrict__ W1, const u16* __restrict__ W2,
               void* Y0, void* Y1, void* Y2,
               const float* __restrict__ cosT, const float* __restrict__ sinT)
{
    __shared__ __align__(16) u16 Al[128 * 32];
    __shared__ __align__(16) u16 Bl[128 * 32];

    const u16* Wm = (blockIdx.z == 0) ? W0 : (blockIdx.z == 1) ? W1 : W2;
    void* Yv      = (blockIdx.z == 0) ? Y0 : (blockIdx.z == 1) ? Y1 : Y2;

    const int t = threadIdx.x;
    const int w = t >> 6, ll = t & 63;
    const int wr = w >> 1, wc = w & 1;
    const int g = ll >> 4, lc = ll & 15;
    const int m0 = blockIdx.x * 128, n0 = blockIdx.y * 128;

    const int srow = t >> 2;
    const int scol = (t & 3) * 8;

    const u16* Xa = X + (size_t)m0 * D;
    const u16* Wa = Wm + (size_t)n0 * D;

    f32x4 acc[4][4];
    #pragma unroll
    for (int i = 0; i < 4; ++i)
        #pragma unroll
        for (int j = 0; j < 4; ++j)
            acc[i][j] = (f32x4){0.f, 0.f, 0.f, 0.f};

    for (int k0 = 0; k0 < D; k0 += 32) {
        gload_lds16(Xa + (size_t)(srow)      * D + k0 + scol, &Al[(w * 64) * 8]);
        gload_lds16(Xa + (size_t)(64 + srow) * D + k0 + scol, &Al[(256 + w * 64) * 8]);
        gload_lds16(Wa + (size_t)(srow)      * D + k0 + scol, &Bl[(w * 64) * 8]);
        gload_lds16(Wa + (size_t)(64 + srow) * D + k0 + scol, &Bl[(256 + w * 64) * 8]);
        __syncthreads();

        bf16x8 af[4], bf[4];
        #pragma unroll
        for (int i = 0; i < 4; ++i)
            af[i] = *(const bf16x8*)&Al[(wr * 64 + i * 16 + lc) * 32 + g * 8];
        #pragma unroll
        for (int j = 0; j < 4; ++j)
            bf[j] = *(const bf16x8*)&Bl[(wc * 64 + j * 16 + lc) * 32 + g * 8];

        #pragma unroll
        for (int i = 0; i < 4; ++i)
            #pragma unroll
            for (int j = 0; j < 4; ++j)
                acc[i][j] = __builtin_amdgcn_mfma_f32_16x16x32_bf16(af[i], bf[j], acc[i][j], 0, 0, 0);
        __syncthreads();
    }

    if (DO_ROPE) {
        const float scale = (blockIdx.z == 0) ? (0.125f * 1.44269504f) : 1.0f;
        u16* Y = (u16*)Yv;
        #pragma unroll
        for (int i = 0; i < 4; ++i)
            #pragma unroll
            for (int r = 0; r < 4; ++r) {
                int row = m0 + wr * 64 + i * 16 + g * 4 + r;
                int s = row & (S - 1);
                #pragma unroll
                for (int jh = 0; jh < 2; ++jh) {
                    float c  = cosT[s * DH + jh * 16 + lc];
                    float sn = sinT[s * DH + jh * 16 + lc];
                    float a0 = acc[i][jh][r], a1 = acc[i][jh + 2][r];
                    size_t base = (size_t)row * D + n0 + wc * 64;
                    Y[base + jh * 16 + lc]       = f2bf((a0 * c - a1 * sn) * scale);
                    Y[base + (jh + 2) * 16 + lc] = f2bf((a1 * c + a0 * sn) * scale);
                }
            }
    } else if (WRITE_BF16) {
        u16* Y = (u16*)Yv;
        #pragma unroll
        for (int i = 0; i < 4; ++i)
            #pragma unroll
            for (int j = 0; j < 4; ++j)
                #pragma unroll
                for (int r = 0; r < 4; ++r) {
                    int row = m0 + wr * 64 + i * 16 + g * 4 + r;
                    int col = n0 + wc * 64 + j * 16 + lc;
                    Y[(size_t)row * D + col] = f2bf(acc[i][j][r]);
                }
    } else {
        float* Y = (float*)Yv;
        #pragma unroll
        for (int i = 0; i < 4; ++i)
            #pragma unroll
            for (int j = 0; j < 4; ++j)
                #pragma unroll
                for (int r = 0; r < 4; ++r) {
                    int row = m0 + wr * 64 + i * 16 + g * 4 + r;
                    int col = n0 + wc * 64 + j * 16 + lc;
                    Y[(size_t)row * D + col] = acc[i][j][r];
                }
    }
}

// ---------------- V transpose (unchanged) ----------------
__global__ __launch_bounds__(256)
void vtrans_kernel(const u16* __restrict__ V, u16* __restrict__ Vt)
{
    __shared__ __align__(16) u16 Tl[64][72];
    const int t = threadIdx.x;
    const int s0 = blockIdx.x * 64;
    const int bh = blockIdx.y;
    const int b = bh >> 4, h = bh & 15;

    int sl = t >> 2, dh0 = (t & 3) * 16;
    const u16* src = &V[(size_t)(b * S + s0 + sl) * D + h * DH + dh0];
    bf16x8 v0 = *(const bf16x8*)src;
    bf16x8 v1 = *(const bf16x8*)(src + 8);
    #pragma unroll
    for (int i = 0; i < 8; ++i) {
        Tl[sl][dh0 + i]     = ((u16*)&v0)[i];
        Tl[sl][dh0 + 8 + i] = ((u16*)&v1)[i];
    }
    __syncthreads();
    int dh = t >> 2, ss0 = (t & 3) * 16;
    union { u16 u[16]; } o;
    #pragma unroll
    for (int i = 0; i < 16; ++i) o.u[i] = Tl[ss0 + i][dh];
    u16* dst = &Vt[((size_t)bh * DH + dh) * S + s0 + ss0];
    *(bf16x8*)dst       = *(bf16x8*)&o.u[0];
    *(bf16x8*)(dst + 8) = *(bf16x8*)&o.u[8];
}

// ---------------- MFMA flash attention, no-max softmax, double-buffered ----
// 2-phase pipeline (T3 minimum recipe): STAGE(next) -> compute(cur) ->
// vmcnt(0) -> raw s_barrier -> swap. Loads fly during the whole compute.
// Epilogue O-transpose aliases the K/V buffers (wave-local, after final barrier).
#define QBLK 128
#define NT (S / 64)

__global__ __launch_bounds__(256)
void attn_mfma(const u16* __restrict__ Q, const u16* __restrict__ Kg,
               const u16* __restrict__ Vt, u16* __restrict__ CTX)
{
    __shared__ __align__(16) u16 smem[16384];   // 32 KB: 2 x (K 8KB + V 8KB)

    const int t  = threadIdx.x;
    const int w  = t >> 6;
    const int q  = t & 31;
    const int hi = (t >> 5) & 1;

    // XCD-chunked swizzle: all 16 q-blocks of a (b,h) on one XCD
    const int bid  = blockIdx.x;          // 0..1023
    const int xcd  = bid & 7;
    const int slot = bid >> 3;            // 0..127
    const int bh   = xcd * 8 + (slot >> 4);
    const int qb   = slot & 15;
    const int b = bh >> 4, h = bh & 15;
    const int q0 = qb * QBLK;

    // Q as B-fragments: qf[c][e] = Q[qrow][16c + 8hi + e] (pre-scaled by cs2)
    bf16x8 qf[4];
    {
        const u16* qp = &Q[(size_t)(b*S + q0 + w*32 + q) * D + h*DH + hi*8];
        qf[0] = *(const bf16x8*)(qp);
        qf[1] = *(const bf16x8*)(qp + 16);
        qf[2] = *(const bf16x8*)(qp + 32);
        qf[3] = *(const bf16x8*)(qp + 48);
    }

    bf16x8 ones;
    {
        union { u16 u[8]; bf16x8 v; } ou;
        #pragma unroll
        for (int i = 0; i < 8; ++i) ou.u[i] = 0x3f80;   // bf16 1.0
        ones = ou.v;
    }

    f32x16 po0, po1, lsum;
    #pragma unroll
    for (int i = 0; i < 16; ++i) { po0[i] = 0.f; po1[i] = 0.f; lsum[i] = 0.f; }

    const int srow = t >> 3;
    const int kbs  = ((t & 7) << 4) ^ ((srow & 7) << 4);
    const int scol = kbs >> 1;
    const int rsw  = (q & 7) << 4;   // read-side swizzle

    u16* Kcur = smem;         u16* Vcur = smem + 4096;
    u16* Knxt = smem + 8192;  u16* Vnxt = smem + 12288;

    const size_t kgbase = (size_t)(b * S) * D + (size_t)h * DH;
    const size_t vtbase = (size_t)bh * DH * S;

    // prologue: stage tile 0, drain, sync
    gload_lds16(&Kg[kgbase + (size_t)(srow) * D + scol],      Kcur + w*512);
    gload_lds16(&Kg[kgbase + (size_t)(32 + srow) * D + scol], Kcur + 2048 + w*512);
    gload_lds16(&Vt[vtbase + (size_t)(srow) * S + scol],      Vcur + w*512);
    gload_lds16(&Vt[vtbase + (size_t)(32 + srow) * S + scol], Vcur + 2048 + w*512);
    asm volatile("s_waitcnt vmcnt(0)" ::: "memory");
    __builtin_amdgcn_s_barrier();

    for (int ti = 0; ti < NT; ++ti) {
        // ---- stage next tile (loads fly during compute) ----
        if (ti + 1 < NT) {
            const int kt = (ti + 1) * 64;
            gload_lds16(&Kg[kgbase + (size_t)(kt + srow) * D + scol],      Knxt + w*512);
            gload_lds16(&Kg[kgbase + (size_t)(kt + 32 + srow) * D + scol], Knxt + 2048 + w*512);
            gload_lds16(&Vt[vtbase + (size_t)(srow) * S + kt + scol],      Vnxt + w*512);
            gload_lds16(&Vt[vtbase + (size_t)(32 + srow) * S + kt + scol], Vnxt + 2048 + w*512);
        }

        // ---- swapped QK^T: p0 = keys 0-31, p1 = keys 32-63 ----
        f32x16 p0, p1;
        #pragma unroll
        for (int i = 0; i < 16; ++i) { p0[i] = 0.f; p1[i] = 0.f; }
        __builtin_amdgcn_s_setprio(1);
        #pragma unroll
        for (int c = 0; c < 4; ++c) {
            int cb = ((c*32 + hi*16) ^ rsw) >> 1;
            bf16x8 k0 = *(const bf16x8*)&Kcur[(q << 6) + cb];
            bf16x8 k1 = *(const bf16x8*)&Kcur[((32 + q) << 6) + cb];
            p0 = __builtin_amdgcn_mfma_f32_32x32x16_bf16(k0, qf[c], p0, 0, 0, 0);
            p1 = __builtin_amdgcn_mfma_f32_32x32x16_bf16(k1, qf[c], p1, 0, 0, 0);
        }
        __builtin_amdgcn_s_setprio(0);

        // ---- P = exp2(score) directly (no max subtraction; Q pre-scaled) ----
        u32 WW[16];
        #pragma unroll
        for (int j = 0; j < 8; ++j) {
            WW[j]     = packbf(exp2_fast(p0[2*j]), exp2_fast(p0[2*j + 1]));
            WW[8 + j] = packbf(exp2_fast(p1[2*j]), exp2_fast(p1[2*j + 1]));
        }

        // ---- B-fragments via permlane32_swap pairs ----
        bf16x8 pa[4];
        #pragma unroll
        for (int ks = 0; ks < 4; ++ks) {
            const int b4 = 4*(ks & 1) + 8*(ks >> 1);
            u32 w0 = WW[b4 + 0], w1 = WW[b4 + 1], w2 = WW[b4 + 2], w3 = WW[b4 + 3];
            plswap(w0, w2);
            plswap(w1, w3);
            union { u32 u[4]; bf16x8 v; } pb;
            pb.u[0] = w0; pb.u[1] = w1; pb.u[2] = w2; pb.u[3] = w3;
            pa[ks] = pb.v;
        }

        // ---- lsum += ones^T x P ;  po += Vt_frag x pa ----
        __builtin_amdgcn_s_setprio(1);
        #pragma unroll
        for (int ks = 0; ks < 4; ++ks)
            lsum = __builtin_amdgcn_mfma_f32_32x32x16_bf16(ones, pa[ks], lsum, 0, 0, 0);
        #pragma unroll
        for (int ks = 0; ks < 4; ++ks) {
            int vb = ((ks*32 + hi*16) ^ rsw) >> 1;
            bf16x8 v0 = *(const bf16x8*)&Vcur[(q << 6) + vb];
            bf16x8 v1 = *(const bf16x8*)&Vcur[((32 + q) << 6) + vb];
            po0 = __builtin_amdgcn_mfma_f32_32x32x16_bf16(v0, pa[ks], po0, 0, 0, 0);
            po1 = __builtin_amdgcn_mfma_f32_32x32x16_bf16(v1, pa[ks], po1, 0, 0, 0);
        }
        __builtin_amdgcn_s_setprio(0);

        // ---- drain prefetch (already landed under compute), sync, swap ----
        asm volatile("s_waitcnt vmcnt(0)" ::: "memory");
        __builtin_amdgcn_s_barrier();
        u16* tk = Kcur; Kcur = Knxt; Knxt = tk;
        u16* tv = Vcur; Vcur = Vnxt; Vnxt = tv;
    }

    // ---- epilogue: normalize, transpose via wave-local LDS (aliases K/V) ----
    float inv = 1.f / lsum[0];
    u16* ow = &smem[w * 2304];   // 32 rows x 72 u16 per wave
    #pragma unroll
    for (int r = 0; r < 16; ++r) {
        int d0 = (r & 3) + 8 * (r >> 2) + 4 * hi;
        ow[q * 72 + d0]      = f2bf(po0[r] * inv);
        ow[q * 72 + 32 + d0] = f2bf(po1[r] * inv);
    }
    int row = (t & 63) >> 1, half = t & 1;
    const u16* orow = &ow[row * 72 + half * 32];
    u16* gp = &CTX[(size_t)(b*S + q0 + w*32 + row) * D + h*DH + half * 32];
    #pragma unroll
    for (int i = 0; i < 4; ++i)
        *(bf16x8*)(gp + i * 8) = *(const bf16x8*)(orow + i * 8);
}

extern "C" void kernel_launch(void* const* d_in, const int* in_sizes, int n_in,
                              void* d_out, int out_size, void* d_ws, size_t ws_size,
                              hipStream_t stream)
{
    const float* x    = (const float*)d_in[0];
    const float* cosT = (const float*)d_in[1];
    const float* sinT = (const float*)d_in[2];
    const float* wq   = (const float*)d_in[3];
    const float* wk   = (const float*)d_in[4];
    const float* wv   = (const float*)d_in[5];
    const float* wo   = (const float*)d_in[6];
    float* out = (float*)d_out;

    const size_t MD = (size_t)M_TOT * D;
    const size_t WD = (size_t)D * D;

    u16* xb   = (u16*)d_ws;
    u16* Qb   = xb + MD;
    u16* Kb   = Qb + MD;
    u16* Vb   = Kb + MD;
    u16* Vtb  = Vb + MD;
    u16* CTXb = Vtb + MD;
    u16* wqb  = CTXb + MD;
    u16* wkb  = wqb + WD;
    u16* wvb  = wkb + WD;
    u16* wob  = wvb + WD;

    cvt_kernel<<<(int)(MD / 8 / 256), 256, 0, stream>>>(x, xb, (int)MD);
    cvt_kernel<<<(int)(WD / 8 / 256), 256, 0, stream>>>(wq, wqb, (int)WD);
    cvt_kernel<<<(int)(WD / 8 / 256), 256, 0, stream>>>(wk, wkb, (int)WD);
    cvt_kernel<<<(int)(WD / 8 / 256), 256, 0, stream>>>(wv, wvb, (int)WD);
    cvt_kernel<<<(int)(WD / 8 / 256), 256, 0, stream>>>(wo, wob, (int)WD);

    // Q,K projections with fused RoPE (Q also pre-scaled by 1/sqrt(DH)*log2e)
    gemm_mfma<1, 1><<<dim3(M_TOT / 128, D / 128, 2), 256, 0, stream>>>(
        xb, wqb, wkb, nullptr, Qb, Kb, nullptr, cosT, sinT);
    // V projection (no rope)
    gemm_mfma<1, 0><<<dim3(M_TOT / 128, D / 128, 1), 256, 0, stream>>>(
        xb, wvb, nullptr, nullptr, Vb, nullptr, nullptr, nullptr, nullptr);

    vtrans_kernel<<<dim3(S / 64, BH), 256, 0, stream>>>(Vb, Vtb);

    attn_mfma<<<dim3(S / QBLK * H * B), 256, 0, stream>>>(Qb, Kb, Vtb, CTXb);

    gemm_mfma<0, 0><<<dim3(M_TOT / 128, D / 128, 1), 256, 0, stream>>>(
        CTXb, wob, nullptr, nullptr, out, nullptr, nullptr, nullptr, nullptr);
}

// Round 7
// 204.432 us; speedup vs baseline: 1.1341x; 1.1341x over previous
//
#include <hip/hip_runtime.h>
#include <hip/hip_bf16.h>
#include <stdint.h>

#define B 4
#define S 2048
#define D 1024
#define H 16
#define DH 64
#define M_TOT (B*S)
#define BH (B*H)

typedef unsigned short u16;
typedef unsigned int u32;
typedef __attribute__((ext_vector_type(4))) float f32x4;
typedef __attribute__((ext_vector_type(16))) float f32x16;
typedef __attribute__((ext_vector_type(8))) short bf16x8;
typedef __attribute__((ext_vector_type(2))) unsigned int u32x2;

typedef const __attribute__((address_space(1))) unsigned int* gp_t;
typedef __attribute__((address_space(3))) unsigned int* lp_t;

__device__ __forceinline__ void gload_lds16(const void* g, void* l) {
    __builtin_amdgcn_global_load_lds((gp_t)g, (lp_t)l, 16, 0, 0);
}

__device__ __forceinline__ float bf2f(u16 u) {
    u32 t = ((u32)u) << 16;
    float f; __builtin_memcpy(&f, &t, 4); return f;
}
__device__ __forceinline__ u16 f2bf(float f) {   // RTNE
    u32 u; __builtin_memcpy(&u, &f, 4);
    u += 0x7fffu + ((u >> 16) & 1u);
    return (u16)(u >> 16);
}
__device__ __forceinline__ u32 packbf(float lo, float hi_) {
    __hip_bfloat162 h = __float22bfloat162_rn(float2{lo, hi_});
    u32 r; __builtin_memcpy(&r, &h, 4); return r;
}

__device__ __forceinline__ float exp2_fast(float x) { return __builtin_amdgcn_exp2f(x); }

#if __has_builtin(__builtin_amdgcn_permlane32_swap)
__device__ __forceinline__ void plswap(u32& a, u32& bb) {
    u32x2 r = __builtin_amdgcn_permlane32_swap(a, bb, false, false);
    a = r.x; bb = r.y;
}
#else
__device__ __forceinline__ void plswap(u32& a, u32& bb) {
    int hi = (threadIdx.x >> 5) & 1;
    u32 ra = (u32)__shfl_xor((int)a, 32);
    u32 rb = (u32)__shfl_xor((int)bb, 32);
    u32 na = hi ? rb : a;
    u32 nb = hi ? bb : ra;
    a = na; bb = nb;
}
#endif

// ---------------- fused fp32 -> bf16 cast for x + 4 weights ----------------
__global__ __launch_bounds__(256)
void cvt_all_kernel(const float* __restrict__ x,
                    const float* __restrict__ wq, const float* __restrict__ wk,
                    const float* __restrict__ wv, const float* __restrict__ wo,
                    u16* __restrict__ xb, u16* __restrict__ wqb, u16* __restrict__ wkb,
                    u16* __restrict__ wvb, u16* __restrict__ wob)
{
    const size_t MD = (size_t)M_TOT * D;
    const size_t WD = (size_t)D * D;       // 2^20
    size_t i = ((size_t)blockIdx.x * 256 + threadIdx.x) * 8;
    const float* src; u16* dst; size_t off;
    if (i < MD) { src = x; dst = xb; off = i; }
    else {
        size_t j = i - MD;
        int wsel = (int)(j >> 20);
        off = j & (WD - 1);
        if      (wsel == 0) { src = wq; dst = wqb; }
        else if (wsel == 1) { src = wk; dst = wkb; }
        else if (wsel == 2) { src = wv; dst = wvb; }
        else                { src = wo; dst = wob; }
    }
    float4 a = *(const float4*)(src + off);
    float4 b = *(const float4*)(src + off + 4);
    union { u16 u[8]; bf16x8 v; } o;
    o.u[0] = f2bf(a.x); o.u[1] = f2bf(a.y); o.u[2] = f2bf(a.z); o.u[3] = f2bf(a.w);
    o.u[4] = f2bf(b.x); o.u[5] = f2bf(b.y); o.u[6] = f2bf(b.z); o.u[7] = f2bf(b.w);
    *(bf16x8*)(dst + off) = o.v;
}

// ---------------- bf16 MFMA GEMM (m97 structure; optional fused RoPE) ------
template<int WRITE_BF16, int DO_ROPE>
__global__ __launch_bounds__(256)
void gemm_mfma(const u16* __restrict__ X,
               const u16* __restrict__ W0, const u16* __restrict__ W1, const u16* __restrict__ W2,
               void* Y0, void* Y1, void* Y2,
               const float* __restrict__ cosT, const float* __restrict__ sinT)
{
    __shared__ __align__(16) u16 Al[128 * 32];
    __shared__ __align__(16) u16 Bl[128 * 32];

    const u16* Wm = (blockIdx.z == 0) ? W0 : (blockIdx.z == 1) ? W1 : W2;
    void* Yv      = (blockIdx.z == 0) ? Y0 : (blockIdx.z == 1) ? Y1 : Y2;

    const int t = threadIdx.x;
    const int w = t >> 6, ll = t & 63;
    const int wr = w >> 1, wc = w & 1;
    const int g = ll >> 4, lc = ll & 15;
    const int m0 = blockIdx.x * 128, n0 = blockIdx.y * 128;

    const int srow = t >> 2;
    const int scol = (t & 3) * 8;

    const u16* Xa = X + (size_t)m0 * D;
    const u16* Wa = Wm + (size_t)n0 * D;

    f32x4 acc[4][4];
    #pragma unroll
    for (int i = 0; i < 4; ++i)
        #pragma unroll
        for (int j = 0; j < 4; ++j)
            acc[i][j] = (f32x4){0.f, 0.f, 0.f, 0.f};

    for (int k0 = 0; k0 < D; k0 += 32) {
        gload_lds16(Xa + (size_t)(srow)      * D + k0 + scol, &Al[(w * 64) * 8]);
        gload_lds16(Xa + (size_t)(64 + srow) * D + k0 + scol, &Al[(256 + w * 64) * 8]);
        gload_lds16(Wa + (size_t)(srow)      * D + k0 + scol, &Bl[(w * 64) * 8]);
        gload_lds16(Wa + (size_t)(64 + srow) * D + k0 + scol, &Bl[(256 + w * 64) * 8]);
        __syncthreads();

        bf16x8 af[4], bf[4];
        #pragma unroll
        for (int i = 0; i < 4; ++i)
            af[i] = *(const bf16x8*)&Al[(wr * 64 + i * 16 + lc) * 32 + g * 8];
        #pragma unroll
        for (int j = 0; j < 4; ++j)
            bf[j] = *(const bf16x8*)&Bl[(wc * 64 + j * 16 + lc) * 32 + g * 8];

        #pragma unroll
        for (int i = 0; i < 4; ++i)
            #pragma unroll
            for (int j = 0; j < 4; ++j)
                acc[i][j] = __builtin_amdgcn_mfma_f32_16x16x32_bf16(af[i], bf[j], acc[i][j], 0, 0, 0);
        __syncthreads();
    }

    if (DO_ROPE) {
        const float scale = (blockIdx.z == 0) ? (0.125f * 1.44269504f) : 1.0f;
        u16* Y = (u16*)Yv;
        #pragma unroll
        for (int i = 0; i < 4; ++i)
            #pragma unroll
            for (int r = 0; r < 4; ++r) {
                int row = m0 + wr * 64 + i * 16 + g * 4 + r;
                int s = row & (S - 1);
                #pragma unroll
                for (int jh = 0; jh < 2; ++jh) {
                    float c  = cosT[s * DH + jh * 16 + lc];
                    float sn = sinT[s * DH + jh * 16 + lc];
                    float a0 = acc[i][jh][r], a1 = acc[i][jh + 2][r];
                    size_t base = (size_t)row * D + n0 + wc * 64;
                    Y[base + jh * 16 + lc]       = f2bf((a0 * c - a1 * sn) * scale);
                    Y[base + (jh + 2) * 16 + lc] = f2bf((a1 * c + a0 * sn) * scale);
                }
            }
    } else if (WRITE_BF16) {
        u16* Y = (u16*)Yv;
        #pragma unroll
        for (int i = 0; i < 4; ++i)
            #pragma unroll
            for (int j = 0; j < 4; ++j)
                #pragma unroll
                for (int r = 0; r < 4; ++r) {
                    int row = m0 + wr * 64 + i * 16 + g * 4 + r;
                    int col = n0 + wc * 64 + j * 16 + lc;
                    Y[(size_t)row * D + col] = f2bf(acc[i][j][r]);
                }
    } else {
        float* Y = (float*)Yv;
        #pragma unroll
        for (int i = 0; i < 4; ++i)
            #pragma unroll
            for (int j = 0; j < 4; ++j)
                #pragma unroll
                for (int r = 0; r < 4; ++r) {
                    int row = m0 + wr * 64 + i * 16 + g * 4 + r;
                    int col = n0 + wc * 64 + j * 16 + lc;
                    Y[(size_t)row * D + col] = acc[i][j][r];
                }
    }
}

// ---------------- V transpose (unchanged) ----------------
__global__ __launch_bounds__(256)
void vtrans_kernel(const u16* __restrict__ V, u16* __restrict__ Vt)
{
    __shared__ __align__(16) u16 Tl[64][72];
    const int t = threadIdx.x;
    const int s0 = blockIdx.x * 64;
    const int bh = blockIdx.y;
    const int b = bh >> 4, h = bh & 15;

    int sl = t >> 2, dh0 = (t & 3) * 16;
    const u16* src = &V[(size_t)(b * S + s0 + sl) * D + h * DH + dh0];
    bf16x8 v0 = *(const bf16x8*)src;
    bf16x8 v1 = *(const bf16x8*)(src + 8);
    #pragma unroll
    for (int i = 0; i < 8; ++i) {
        Tl[sl][dh0 + i]     = ((u16*)&v0)[i];
        Tl[sl][dh0 + 8 + i] = ((u16*)&v1)[i];
    }
    __syncthreads();
    int dh = t >> 2, ss0 = (t & 3) * 16;
    union { u16 u[16]; } o;
    #pragma unroll
    for (int i = 0; i < 16; ++i) o.u[i] = Tl[ss0 + i][dh];
    u16* dst = &Vt[((size_t)bh * DH + dh) * S + s0 + ss0];
    *(bf16x8*)dst       = *(bf16x8*)&o.u[0];
    *(bf16x8*)(dst + 8) = *(bf16x8*)&o.u[8];
}

// ---------------- MFMA flash attention: 64 q-rows/wave, no-max softmax -----
// QBLK=256 = 4 waves x 64 q-rows. Each K/V fragment read feeds 2 MFMAs
// (two q-groups) -> LDS read traffic halved vs 32q/wave. Double-buffered
// K/V tiles, unroll-2 so all LDS read addresses are loop-invariant.
#define QBLK 256
#define NT (S / 64)

__global__ __launch_bounds__(256, 2)
void attn_mfma(const u16* __restrict__ Q, const u16* __restrict__ Kg,
               const u16* __restrict__ Vt, u16* __restrict__ CTX)
{
    __shared__ __align__(16) u16 smem[16384];   // 2 x (K 8KB + V 8KB)

    const int t  = threadIdx.x;
    const int w  = t >> 6;
    const int q  = t & 31;
    const int hi = (t >> 5) & 1;

    // XCD-chunked swizzle: 8 bh per XCD (KV working set = 4MB = one L2)
    const int bid  = blockIdx.x;          // 0..511
    const int xcd  = bid & 7;
    const int slot = bid >> 3;            // 0..63
    const int bh   = xcd * 8 + (slot >> 3);
    const int qb   = slot & 7;
    const int b = bh >> 4, h = bh & 15;
    const int q0 = qb * QBLK;
    const int qbase = q0 + w * 64;

    // Q as B-fragments for 2 q-groups: qf[qg][c][e] = Q[qbase+32qg+q][16c+8hi+e]
    bf16x8 qf[2][4];
    #pragma unroll
    for (int qg = 0; qg < 2; ++qg) {
        const u16* qp = &Q[(size_t)(b*S + qbase + qg*32 + q) * D + h*DH + hi*8];
        qf[qg][0] = *(const bf16x8*)(qp);
        qf[qg][1] = *(const bf16x8*)(qp + 16);
        qf[qg][2] = *(const bf16x8*)(qp + 32);
        qf[qg][3] = *(const bf16x8*)(qp + 48);
    }

    bf16x8 ones;
    {
        union { u16 u[8]; bf16x8 v; } ou;
        #pragma unroll
        for (int i = 0; i < 8; ++i) ou.u[i] = 0x3f80;   // bf16 1.0
        ones = ou.v;
    }

    f32x16 po[4], lsum[2];   // po[qg*2+dhalf]
    #pragma unroll
    for (int i = 0; i < 16; ++i) {
        po[0][i] = 0.f; po[1][i] = 0.f; po[2][i] = 0.f; po[3][i] = 0.f;
        lsum[0][i] = 0.f; lsum[1][i] = 0.f;
    }

    const int srow = t >> 3;
    const int kbs  = ((t & 7) << 4) ^ ((srow & 7) << 4);
    const int scol = kbs >> 1;
    const int rsw  = (q & 7) << 4;   // read-side swizzle

    u16* buf0 = smem;
    u16* buf1 = smem + 8192;

    // running global pointers (no per-tile 64-bit address math)
    const u16* kg = Kg + ((size_t)(b * S) + srow) * D + (size_t)h * DH + scol;
    const u16* vg = Vt + ((size_t)bh * DH + srow) * S + scol;
    const size_t KADV = (size_t)64 * D;

    #define STAGE(dst) do {                                   \
        gload_lds16(kg,           (dst) + w*512);             \
        gload_lds16(kg + 32*D,    (dst) + 2048 + w*512);      \
        gload_lds16(vg,           (dst) + 4096 + w*512);      \
        gload_lds16(vg + 32*S,    (dst) + 4096 + 2048 + w*512); \
        kg += KADV; vg += 64; } while (0)

    auto compute = [&](const u16* base) {
        const u16* Kl = base;
        const u16* Vl = base + 4096;
        // ---- swapped QK^T: p[qg][kh] ----
        f32x16 p00, p01, p10, p11;
        #pragma unroll
        for (int i = 0; i < 16; ++i) { p00[i]=0.f; p01[i]=0.f; p10[i]=0.f; p11[i]=0.f; }
        __builtin_amdgcn_s_setprio(1);
        #pragma unroll
        for (int c = 0; c < 4; ++c) {
            int cb = ((c*32 + hi*16) ^ rsw) >> 1;
            bf16x8 k0 = *(const bf16x8*)&Kl[(q << 6) + cb];
            bf16x8 k1 = *(const bf16x8*)&Kl[((32 + q) << 6) + cb];
            p00 = __builtin_amdgcn_mfma_f32_32x32x16_bf16(k0, qf[0][c], p00, 0, 0, 0);
            p01 = __builtin_amdgcn_mfma_f32_32x32x16_bf16(k1, qf[0][c], p01, 0, 0, 0);
            p10 = __builtin_amdgcn_mfma_f32_32x32x16_bf16(k0, qf[1][c], p10, 0, 0, 0);
            p11 = __builtin_amdgcn_mfma_f32_32x32x16_bf16(k1, qf[1][c], p11, 0, 0, 0);
        }
        __builtin_amdgcn_s_setprio(0);

        // ---- P = exp2(score); pack to bf16 B-fragments per q-group ----
        bf16x8 pa[2][4];
        #pragma unroll
        for (int qg = 0; qg < 2; ++qg) {
            const f32x16& e0 = qg ? p10 : p00;
            const f32x16& e1 = qg ? p11 : p01;
            u32 WW[16];
            #pragma unroll
            for (int j = 0; j < 8; ++j) {
                WW[j]     = packbf(exp2_fast(e0[2*j]), exp2_fast(e0[2*j + 1]));
                WW[8 + j] = packbf(exp2_fast(e1[2*j]), exp2_fast(e1[2*j + 1]));
            }
            #pragma unroll
            for (int ks = 0; ks < 4; ++ks) {
                const int b4 = 4*(ks & 1) + 8*(ks >> 1);
                u32 w0 = WW[b4 + 0], w1 = WW[b4 + 1], w2 = WW[b4 + 2], w3 = WW[b4 + 3];
                plswap(w0, w2);
                plswap(w1, w3);
                union { u32 u[4]; bf16x8 v; } pb;
                pb.u[0] = w0; pb.u[1] = w1; pb.u[2] = w2; pb.u[3] = w3;
                pa[qg][ks] = pb.v;
            }
        }

        // ---- lsum += ones^T x P ;  po += Vt_frag x pa ----
        __builtin_amdgcn_s_setprio(1);
        #pragma unroll
        for (int ks = 0; ks < 4; ++ks) {
            lsum[0] = __builtin_amdgcn_mfma_f32_32x32x16_bf16(ones, pa[0][ks], lsum[0], 0, 0, 0);
            lsum[1] = __builtin_amdgcn_mfma_f32_32x32x16_bf16(ones, pa[1][ks], lsum[1], 0, 0, 0);
        }
        #pragma unroll
        for (int ks = 0; ks < 4; ++ks) {
            int vb = ((ks*32 + hi*16) ^ rsw) >> 1;
            bf16x8 v0 = *(const bf16x8*)&Vl[(q << 6) + vb];
            bf16x8 v1 = *(const bf16x8*)&Vl[((32 + q) << 6) + vb];
            po[0] = __builtin_amdgcn_mfma_f32_32x32x16_bf16(v0, pa[0][ks], po[0], 0, 0, 0);
            po[1] = __builtin_amdgcn_mfma_f32_32x32x16_bf16(v1, pa[0][ks], po[1], 0, 0, 0);
            po[2] = __builtin_amdgcn_mfma_f32_32x32x16_bf16(v0, pa[1][ks], po[2], 0, 0, 0);
            po[3] = __builtin_amdgcn_mfma_f32_32x32x16_bf16(v1, pa[1][ks], po[3], 0, 0, 0);
        }
        __builtin_amdgcn_s_setprio(0);
    };

    // prologue: stage tile 0
    STAGE(buf0);
    asm volatile("s_waitcnt vmcnt(0)" ::: "memory");
    __builtin_amdgcn_s_barrier();

    for (int ti = 0; ti < NT; ti += 2) {
        STAGE(buf1);                       // tile ti+1
        compute(buf0);                     // tile ti
        asm volatile("s_waitcnt vmcnt(0)" ::: "memory");
        __builtin_amdgcn_s_barrier();
        if (ti < NT - 2) STAGE(buf0);      // tile ti+2
        compute(buf1);                     // tile ti+1
        asm volatile("s_waitcnt vmcnt(0)" ::: "memory");
        __builtin_amdgcn_s_barrier();
    }
    #undef STAGE

    // ---- epilogue: per q-group normalize + transpose via wave-local LDS ----
    u16* ow = &smem[w * 2304];   // 32 rows x 72 u16 per wave (wave-local)
    #pragma unroll
    for (int qg = 0; qg < 2; ++qg) {
        float inv = 1.f / lsum[qg][0];
        #pragma unroll
        for (int r = 0; r < 16; ++r) {
            int d0 = (r & 3) + 8 * (r >> 2) + 4 * hi;
            ow[q * 72 + d0]      = f2bf(po[qg*2 + 0][r] * inv);
            ow[q * 72 + 32 + d0] = f2bf(po[qg*2 + 1][r] * inv);
        }
        int row = (t & 63) >> 1, half = t & 1;
        const u16* orow = &ow[row * 72 + half * 32];
        u16* gp = &CTX[(size_t)(b*S + qbase + qg*32 + row) * D + h*DH + half * 32];
        #pragma unroll
        for (int i = 0; i < 4; ++i)
            *(bf16x8*)(gp + i * 8) = *(const bf16x8*)(orow + i * 8);
    }
}

extern "C" void kernel_launch(void* const* d_in, const int* in_sizes, int n_in,
                              void* d_out, int out_size, void* d_ws, size_t ws_size,
                              hipStream_t stream)
{
    const float* x    = (const float*)d_in[0];
    const float* cosT = (const float*)d_in[1];
    const float* sinT = (const float*)d_in[2];
    const float* wq   = (const float*)d_in[3];
    const float* wk   = (const float*)d_in[4];
    const float* wv   = (const float*)d_in[5];
    const float* wo   = (const float*)d_in[6];
    float* out = (float*)d_out;

    const size_t MD = (size_t)M_TOT * D;
    const size_t WD = (size_t)D * D;

    u16* xb   = (u16*)d_ws;
    u16* Qb   = xb + MD;
    u16* Kb   = Qb + MD;
    u16* Vb   = Kb + MD;
    u16* Vtb  = Vb + MD;
    u16* CTXb = Vtb + MD;
    u16* wqb  = CTXb + MD;
    u16* wkb  = wqb + WD;
    u16* wvb  = wkb + WD;
    u16* wob  = wvb + WD;

    // 1. fused bf16 casts (x + 4 weights in one launch)
    cvt_all_kernel<<<(int)((MD + 4*WD) / 8 / 256), 256, 0, stream>>>(
        x, wq, wk, wv, wo, xb, wqb, wkb, wvb, wob);

    // 2. Q,K projections with fused RoPE (Q also pre-scaled by 1/sqrt(DH)*log2e)
    gemm_mfma<1, 1><<<dim3(M_TOT / 128, D / 128, 2), 256, 0, stream>>>(
        xb, wqb, wkb, nullptr, Qb, Kb, nullptr, cosT, sinT);
    // 3. V projection (no rope)
    gemm_mfma<1, 0><<<dim3(M_TOT / 128, D / 128, 1), 256, 0, stream>>>(
        xb, wvb, nullptr, nullptr, Vb, nullptr, nullptr, nullptr, nullptr);

    // 4. transpose V
    vtrans_kernel<<<dim3(S / 64, BH), 256, 0, stream>>>(Vb, Vtb);

    // 5. attention
    attn_mfma<<<dim3(M_TOT / QBLK * H), 256, 0, stream>>>(Qb, Kb, Vtb, CTXb);

    // 6. output projection (fp32 out)
    gemm_mfma<0, 0><<<dim3(M_TOT / 128, D / 128, 1), 256, 0, stream>>>(
        CTXb, wob, nullptr, nullptr, out, nullptr, nullptr, nullptr, nullptr);
}

// Round 8
// 202.538 us; speedup vs baseline: 1.1447x; 1.0094x over previous
//
#include <hip/hip_runtime.h>
#include <hip/hip_bf16.h>
#include <stdint.h>

#define B 4
#define S 2048
#define D 1024
#define H 16
#define DH 64
#define M_TOT (B*S)
#define BH (B*H)

typedef unsigned short u16;
typedef unsigned int u32;
typedef __attribute__((ext_vector_type(4))) float f32x4;
typedef __attribute__((ext_vector_type(16))) float f32x16;
typedef __attribute__((ext_vector_type(8))) short bf16x8;
typedef __attribute__((ext_vector_type(2))) unsigned int u32x2;

typedef const __attribute__((address_space(1))) unsigned int* gp_t;
typedef __attribute__((address_space(3))) unsigned int* lp_t;

__device__ __forceinline__ void gload_lds16(const void* g, void* l) {
    __builtin_amdgcn_global_load_lds((gp_t)g, (lp_t)l, 16, 0, 0);
}

__device__ __forceinline__ float bf2f(u16 u) {
    u32 t = ((u32)u) << 16;
    float f; __builtin_memcpy(&f, &t, 4); return f;
}
__device__ __forceinline__ u16 f2bf(float f) {   // RTNE
    u32 u; __builtin_memcpy(&u, &f, 4);
    u += 0x7fffu + ((u >> 16) & 1u);
    return (u16)(u >> 16);
}
__device__ __forceinline__ u32 packbf(float lo, float hi_) {
    __hip_bfloat162 h = __float22bfloat162_rn(float2{lo, hi_});
    u32 r; __builtin_memcpy(&r, &h, 4); return r;
}

__device__ __forceinline__ float exp2_fast(float x) { return __builtin_amdgcn_exp2f(x); }

#if __has_builtin(__builtin_amdgcn_permlane32_swap)
__device__ __forceinline__ void plswap(u32& a, u32& bb) {
    u32x2 r = __builtin_amdgcn_permlane32_swap(a, bb, false, false);
    a = r.x; bb = r.y;
}
#else
__device__ __forceinline__ void plswap(u32& a, u32& bb) {
    int hi = (threadIdx.x >> 5) & 1;
    u32 ra = (u32)__shfl_xor((int)a, 32);
    u32 rb = (u32)__shfl_xor((int)bb, 32);
    u32 na = hi ? rb : a;
    u32 nb = hi ? bb : ra;
    a = na; bb = nb;
}
#endif

// ---------------- fused fp32 -> bf16 cast for x + 4 weights ----------------
__global__ __launch_bounds__(256)
void cvt_all_kernel(const float* __restrict__ x,
                    const float* __restrict__ wq, const float* __restrict__ wk,
                    const float* __restrict__ wv, const float* __restrict__ wo,
                    u16* __restrict__ xb, u16* __restrict__ wqb, u16* __restrict__ wkb,
                    u16* __restrict__ wvb, u16* __restrict__ wob)
{
    const size_t MD = (size_t)M_TOT * D;
    const size_t WD = (size_t)D * D;       // 2^20
    size_t i = ((size_t)blockIdx.x * 256 + threadIdx.x) * 8;
    const float* src; u16* dst; size_t off;
    if (i < MD) { src = x; dst = xb; off = i; }
    else {
        size_t j = i - MD;
        int wsel = (int)(j >> 20);
        off = j & (WD - 1);
        if      (wsel == 0) { src = wq; dst = wqb; }
        else if (wsel == 1) { src = wk; dst = wkb; }
        else if (wsel == 2) { src = wv; dst = wvb; }
        else                { src = wo; dst = wob; }
    }
    float4 a = *(const float4*)(src + off);
    float4 b = *(const float4*)(src + off + 4);
    union { u16 u[8]; bf16x8 v; } o;
    o.u[0] = f2bf(a.x); o.u[1] = f2bf(a.y); o.u[2] = f2bf(a.z); o.u[3] = f2bf(a.w);
    o.u[4] = f2bf(b.x); o.u[5] = f2bf(b.y); o.u[6] = f2bf(b.z); o.u[7] = f2bf(b.w);
    *(bf16x8*)(dst + off) = o.v;
}

// ---------------- bf16 MFMA GEMM (m97 structure; optional fused RoPE) ------
// DO_ROPE: z=0 -> rope+cs2 scale (Q), z=1 -> rope (K), z=2 -> plain bf16 (V).
template<int WRITE_BF16, int DO_ROPE>
__global__ __launch_bounds__(256)
void gemm_mfma(const u16* __restrict__ X,
               const u16* __restrict__ W0, const u16* __restrict__ W1, const u16* __restrict__ W2,
               void* Y0, void* Y1, void* Y2,
               const float* __restrict__ cosT, const float* __restrict__ sinT)
{
    __shared__ __align__(16) u16 Al[128 * 32];
    __shared__ __align__(16) u16 Bl[128 * 32];

    const u16* Wm = (blockIdx.z == 0) ? W0 : (blockIdx.z == 1) ? W1 : W2;
    void* Yv      = (blockIdx.z == 0) ? Y0 : (blockIdx.z == 1) ? Y1 : Y2;

    const int t = threadIdx.x;
    const int w = t >> 6, ll = t & 63;
    const int wr = w >> 1, wc = w & 1;
    const int g = ll >> 4, lc = ll & 15;
    const int m0 = blockIdx.x * 128, n0 = blockIdx.y * 128;

    const int srow = t >> 2;
    const int scol = (t & 3) * 8;

    const u16* Xa = X + (size_t)m0 * D;
    const u16* Wa = Wm + (size_t)n0 * D;

    f32x4 acc[4][4];
    #pragma unroll
    for (int i = 0; i < 4; ++i)
        #pragma unroll
        for (int j = 0; j < 4; ++j)
            acc[i][j] = (f32x4){0.f, 0.f, 0.f, 0.f};

    for (int k0 = 0; k0 < D; k0 += 32) {
        gload_lds16(Xa + (size_t)(srow)      * D + k0 + scol, &Al[(w * 64) * 8]);
        gload_lds16(Xa + (size_t)(64 + srow) * D + k0 + scol, &Al[(256 + w * 64) * 8]);
        gload_lds16(Wa + (size_t)(srow)      * D + k0 + scol, &Bl[(w * 64) * 8]);
        gload_lds16(Wa + (size_t)(64 + srow) * D + k0 + scol, &Bl[(256 + w * 64) * 8]);
        __syncthreads();

        bf16x8 af[4], bf[4];
        #pragma unroll
        for (int i = 0; i < 4; ++i)
            af[i] = *(const bf16x8*)&Al[(wr * 64 + i * 16 + lc) * 32 + g * 8];
        #pragma unroll
        for (int j = 0; j < 4; ++j)
            bf[j] = *(const bf16x8*)&Bl[(wc * 64 + j * 16 + lc) * 32 + g * 8];

        #pragma unroll
        for (int i = 0; i < 4; ++i)
            #pragma unroll
            for (int j = 0; j < 4; ++j)
                acc[i][j] = __builtin_amdgcn_mfma_f32_16x16x32_bf16(af[i], bf[j], acc[i][j], 0, 0, 0);
        __syncthreads();
    }

    if (DO_ROPE && blockIdx.z < 2) {
        const float scale = (blockIdx.z == 0) ? (0.125f * 1.44269504f) : 1.0f;
        u16* Y = (u16*)Yv;
        #pragma unroll
        for (int i = 0; i < 4; ++i)
            #pragma unroll
            for (int r = 0; r < 4; ++r) {
                int row = m0 + wr * 64 + i * 16 + g * 4 + r;
                int s = row & (S - 1);
                #pragma unroll
                for (int jh = 0; jh < 2; ++jh) {
                    float c  = cosT[s * DH + jh * 16 + lc];
                    float sn = sinT[s * DH + jh * 16 + lc];
                    float a0 = acc[i][jh][r], a1 = acc[i][jh + 2][r];
                    size_t base = (size_t)row * D + n0 + wc * 64;
                    Y[base + jh * 16 + lc]       = f2bf((a0 * c - a1 * sn) * scale);
                    Y[base + (jh + 2) * 16 + lc] = f2bf((a1 * c + a0 * sn) * scale);
                }
            }
    } else if (WRITE_BF16) {
        u16* Y = (u16*)Yv;
        #pragma unroll
        for (int i = 0; i < 4; ++i)
            #pragma unroll
            for (int j = 0; j < 4; ++j)
                #pragma unroll
                for (int r = 0; r < 4; ++r) {
                    int row = m0 + wr * 64 + i * 16 + g * 4 + r;
                    int col = n0 + wc * 64 + j * 16 + lc;
                    Y[(size_t)row * D + col] = f2bf(acc[i][j][r]);
                }
    } else {
        float* Y = (float*)Yv;
        #pragma unroll
        for (int i = 0; i < 4; ++i)
            #pragma unroll
            for (int j = 0; j < 4; ++j)
                #pragma unroll
                for (int r = 0; r < 4; ++r) {
                    int row = m0 + wr * 64 + i * 16 + g * 4 + r;
                    int col = n0 + wc * 64 + j * 16 + lc;
                    Y[(size_t)row * D + col] = acc[i][j][r];
                }
    }
}

// ---------------- V transpose (unchanged) ----------------
__global__ __launch_bounds__(256)
void vtrans_kernel(const u16* __restrict__ V, u16* __restrict__ Vt)
{
    __shared__ __align__(16) u16 Tl[64][72];
    const int t = threadIdx.x;
    const int s0 = blockIdx.x * 64;
    const int bh = blockIdx.y;
    const int b = bh >> 4, h = bh & 15;

    int sl = t >> 2, dh0 = (t & 3) * 16;
    const u16* src = &V[(size_t)(b * S + s0 + sl) * D + h * DH + dh0];
    bf16x8 v0 = *(const bf16x8*)src;
    bf16x8 v1 = *(const bf16x8*)(src + 8);
    #pragma unroll
    for (int i = 0; i < 8; ++i) {
        Tl[sl][dh0 + i]     = ((u16*)&v0)[i];
        Tl[sl][dh0 + 8 + i] = ((u16*)&v1)[i];
    }
    __syncthreads();
    int dh = t >> 2, ss0 = (t & 3) * 16;
    union { u16 u[16]; } o;
    #pragma unroll
    for (int i = 0; i < 16; ++i) o.u[i] = Tl[ss0 + i][dh];
    u16* dst = &Vt[((size_t)bh * DH + dh) * S + s0 + ss0];
    *(bf16x8*)dst       = *(bf16x8*)&o.u[0];
    *(bf16x8*)(dst + 8) = *(bf16x8*)&o.u[8];
}

// ---------------- MFMA flash attention: 64 q-rows/wave, pipelined halves ---
// Per tile: QK0 -> QK1 -> pack0 -> [PV0 MFMA || pack1 VALU] -> PV1.
// pack1 is independent of PV0, so scheduler can co-issue VALU + MFMA.
// First MFMA of each score chain uses a persistent zero C (no per-tile init).
#define QBLK 256
#define NT (S / 64)

__global__ __launch_bounds__(256, 2)
void attn_mfma(const u16* __restrict__ Q, const u16* __restrict__ Kg,
               const u16* __restrict__ Vt, u16* __restrict__ CTX)
{
    __shared__ __align__(16) u16 smem[16384];   // 2 x (K 8KB + V 8KB)

    const int t  = threadIdx.x;
    const int w  = t >> 6;
    const int q  = t & 31;
    const int hi = (t >> 5) & 1;

    // XCD-chunked swizzle: 8 bh per XCD (KV working set = 4MB = one L2)
    const int bid  = blockIdx.x;          // 0..511
    const int xcd  = bid & 7;
    const int slot = bid >> 3;            // 0..63
    const int bh   = xcd * 8 + (slot >> 3);
    const int qb   = slot & 7;
    const int b = bh >> 4, h = bh & 15;
    const int q0 = qb * QBLK;
    const int qbase = q0 + w * 64;

    // Q as B-fragments for 2 q-groups
    bf16x8 qf[2][4];
    #pragma unroll
    for (int qg = 0; qg < 2; ++qg) {
        const u16* qp = &Q[(size_t)(b*S + qbase + qg*32 + q) * D + h*DH + hi*8];
        qf[qg][0] = *(const bf16x8*)(qp);
        qf[qg][1] = *(const bf16x8*)(qp + 16);
        qf[qg][2] = *(const bf16x8*)(qp + 32);
        qf[qg][3] = *(const bf16x8*)(qp + 48);
    }

    bf16x8 ones;
    {
        union { u16 u[8]; bf16x8 v; } ou;
        #pragma unroll
        for (int i = 0; i < 8; ++i) ou.u[i] = 0x3f80;   // bf16 1.0
        ones = ou.v;
    }

    f32x16 po[4], lsum[2], zv;
    #pragma unroll
    for (int i = 0; i < 16; ++i) {
        po[0][i] = 0.f; po[1][i] = 0.f; po[2][i] = 0.f; po[3][i] = 0.f;
        lsum[0][i] = 0.f; lsum[1][i] = 0.f; zv[i] = 0.f;
    }

    const int srow = t >> 3;
    const int kbs  = ((t & 7) << 4) ^ ((srow & 7) << 4);
    const int scol = kbs >> 1;
    const int rsw  = (q & 7) << 4;   // read-side swizzle

    u16* buf0 = smem;
    u16* buf1 = smem + 8192;

    const u16* kg = Kg + ((size_t)(b * S) + srow) * D + (size_t)h * DH + scol;
    const u16* vg = Vt + ((size_t)bh * DH + srow) * S + scol;
    const size_t KADV = (size_t)64 * D;

    #define STAGE(dst) do {                                   \
        gload_lds16(kg,           (dst) + w*512);             \
        gload_lds16(kg + 32*D,    (dst) + 2048 + w*512);      \
        gload_lds16(vg,           (dst) + 4096 + w*512);      \
        gload_lds16(vg + 32*S,    (dst) + 4096 + 2048 + w*512); \
        kg += KADV; vg += 64; } while (0)

    // pack half: 2 q-groups x 8 words -> pa[qg][ks0], pa[qg][ks0+... ]
    #define PACK_HALF(pqg0, pqg1, pa00, pa01, pa10, pa11) do {            \
        u32 W0[8], W1[8];                                                  \
        _Pragma("unroll")                                                  \
        for (int j = 0; j < 8; ++j) {                                      \
            W0[j] = packbf(exp2_fast((pqg0)[2*j]), exp2_fast((pqg0)[2*j+1]));\
            W1[j] = packbf(exp2_fast((pqg1)[2*j]), exp2_fast((pqg1)[2*j+1]));\
        }                                                                  \
        plswap(W0[0], W0[2]); plswap(W0[1], W0[3]);                        \
        plswap(W0[4], W0[6]); plswap(W0[5], W0[7]);                        \
        plswap(W1[0], W1[2]); plswap(W1[1], W1[3]);                        \
        plswap(W1[4], W1[6]); plswap(W1[5], W1[7]);                        \
        { union { u32 u[4]; bf16x8 v; } pb;                                \
          pb.u[0]=W0[0]; pb.u[1]=W0[1]; pb.u[2]=W0[2]; pb.u[3]=W0[3]; (pa00)=pb.v; \
          pb.u[0]=W0[4]; pb.u[1]=W0[5]; pb.u[2]=W0[6]; pb.u[3]=W0[7]; (pa01)=pb.v; \
          pb.u[0]=W1[0]; pb.u[1]=W1[1]; pb.u[2]=W1[2]; pb.u[3]=W1[3]; (pa10)=pb.v; \
          pb.u[0]=W1[4]; pb.u[1]=W1[5]; pb.u[2]=W1[6]; pb.u[3]=W1[7]; (pa11)=pb.v; } \
    } while (0)

    auto compute = [&](const u16* base) {
        const u16* Kl = base;
        const u16* Vl = base + 4096;

        // ---- QK half 0 (keys 0-31): k0 rows ----
        f32x16 p00, p10, p01, p11;
        {
            bf16x8 k0[4];
            #pragma unroll
            for (int c = 0; c < 4; ++c)
                k0[c] = *(const bf16x8*)&Kl[(q << 6) + ((( c*32 + hi*16) ^ rsw) >> 1)];
            __builtin_amdgcn_s_setprio(1);
            p00 = __builtin_amdgcn_mfma_f32_32x32x16_bf16(k0[0], qf[0][0], zv, 0, 0, 0);
            p10 = __builtin_amdgcn_mfma_f32_32x32x16_bf16(k0[0], qf[1][0], zv, 0, 0, 0);
            #pragma unroll
            for (int c = 1; c < 4; ++c) {
                p00 = __builtin_amdgcn_mfma_f32_32x32x16_bf16(k0[c], qf[0][c], p00, 0, 0, 0);
                p10 = __builtin_amdgcn_mfma_f32_32x32x16_bf16(k0[c], qf[1][c], p10, 0, 0, 0);
            }
            __builtin_amdgcn_s_setprio(0);
        }
        // ---- QK half 1 (keys 32-63): k1 rows ----
        {
            bf16x8 k1[4];
            #pragma unroll
            for (int c = 0; c < 4; ++c)
                k1[c] = *(const bf16x8*)&Kl[((32 + q) << 6) + (((c*32 + hi*16) ^ rsw) >> 1)];
            __builtin_amdgcn_s_setprio(1);
            p01 = __builtin_amdgcn_mfma_f32_32x32x16_bf16(k1[0], qf[0][0], zv, 0, 0, 0);
            p11 = __builtin_amdgcn_mfma_f32_32x32x16_bf16(k1[0], qf[1][0], zv, 0, 0, 0);
            #pragma unroll
            for (int c = 1; c < 4; ++c) {
                p01 = __builtin_amdgcn_mfma_f32_32x32x16_bf16(k1[c], qf[0][c], p01, 0, 0, 0);
                p11 = __builtin_amdgcn_mfma_f32_32x32x16_bf16(k1[c], qf[1][c], p11, 0, 0, 0);
            }
            __builtin_amdgcn_s_setprio(0);
        }

        // ---- pack half 0 (keys 0-31) ----
        bf16x8 pa00, pa01, pa10, pa11;   // [qg][ks]
        PACK_HALF(p00, p10, pa00, pa01, pa10, pa11);

        // V fragment addresses per ks
        // ---- PV half 0 (ks=0,1) -- interleavable with pack half 1 below ----
        __builtin_amdgcn_s_setprio(1);
        #pragma unroll
        for (int ks = 0; ks < 2; ++ks) {
            int vb = ((ks*32 + hi*16) ^ rsw) >> 1;
            bf16x8 v0 = *(const bf16x8*)&Vl[(q << 6) + vb];
            bf16x8 v1 = *(const bf16x8*)&Vl[((32 + q) << 6) + vb];
            bf16x8 paq0 = ks ? pa01 : pa00;
            bf16x8 paq1 = ks ? pa11 : pa10;
            lsum[0] = __builtin_amdgcn_mfma_f32_32x32x16_bf16(ones, paq0, lsum[0], 0, 0, 0);
            lsum[1] = __builtin_amdgcn_mfma_f32_32x32x16_bf16(ones, paq1, lsum[1], 0, 0, 0);
            po[0] = __builtin_amdgcn_mfma_f32_32x32x16_bf16(v0, paq0, po[0], 0, 0, 0);
            po[1] = __builtin_amdgcn_mfma_f32_32x32x16_bf16(v1, paq0, po[1], 0, 0, 0);
            po[2] = __builtin_amdgcn_mfma_f32_32x32x16_bf16(v0, paq1, po[2], 0, 0, 0);
            po[3] = __builtin_amdgcn_mfma_f32_32x32x16_bf16(v1, paq1, po[3], 0, 0, 0);
        }
        __builtin_amdgcn_s_setprio(0);

        // ---- pack half 1 (keys 32-63) -- independent of PV half 0 ----
        bf16x8 pb00, pb01, pb10, pb11;
        PACK_HALF(p01, p11, pb00, pb01, pb10, pb11);

        // ---- PV half 1 (ks=2,3) ----
        __builtin_amdgcn_s_setprio(1);
        #pragma unroll
        for (int ks = 0; ks < 2; ++ks) {
            int vb = (((ks + 2)*32 + hi*16) ^ rsw) >> 1;
            bf16x8 v0 = *(const bf16x8*)&Vl[(q << 6) + vb];
            bf16x8 v1 = *(const bf16x8*)&Vl[((32 + q) << 6) + vb];
            bf16x8 paq0 = ks ? pb01 : pb00;
            bf16x8 paq1 = ks ? pb11 : pb10;
            lsum[0] = __builtin_amdgcn_mfma_f32_32x32x16_bf16(ones, paq0, lsum[0], 0, 0, 0);
            lsum[1] = __builtin_amdgcn_mfma_f32_32x32x16_bf16(ones, paq1, lsum[1], 0, 0, 0);
            po[0] = __builtin_amdgcn_mfma_f32_32x32x16_bf16(v0, paq0, po[0], 0, 0, 0);
            po[1] = __builtin_amdgcn_mfma_f32_32x32x16_bf16(v1, paq0, po[1], 0, 0, 0);
            po[2] = __builtin_amdgcn_mfma_f32_32x32x16_bf16(v0, paq1, po[2], 0, 0, 0);
            po[3] = __builtin_amdgcn_mfma_f32_32x32x16_bf16(v1, paq1, po[3], 0, 0, 0);
        }
        __builtin_amdgcn_s_setprio(0);
    };

    // prologue: stage tile 0
    STAGE(buf0);
    asm volatile("s_waitcnt vmcnt(0)" ::: "memory");
    __builtin_amdgcn_s_barrier();

    for (int ti = 0; ti < NT; ti += 2) {
        STAGE(buf1);                       // tile ti+1
        compute(buf0);                     // tile ti
        asm volatile("s_waitcnt vmcnt(0)" ::: "memory");
        __builtin_amdgcn_s_barrier();
        if (ti < NT - 2) STAGE(buf0);      // tile ti+2
        compute(buf1);                     // tile ti+1
        asm volatile("s_waitcnt vmcnt(0)" ::: "memory");
        __builtin_amdgcn_s_barrier();
    }
    #undef STAGE
    #undef PACK_HALF

    // ---- epilogue: per q-group normalize + transpose via wave-local LDS ----
    u16* ow = &smem[w * 2304];   // 32 rows x 72 u16 per wave (wave-local)
    #pragma unroll
    for (int qg = 0; qg < 2; ++qg) {
        float inv = 1.f / lsum[qg][0];
        #pragma unroll
        for (int r = 0; r < 16; ++r) {
            int d0 = (r & 3) + 8 * (r >> 2) + 4 * hi;
            ow[q * 72 + d0]      = f2bf(po[qg*2 + 0][r] * inv);
            ow[q * 72 + 32 + d0] = f2bf(po[qg*2 + 1][r] * inv);
        }
        int row = (t & 63) >> 1, half = t & 1;
        const u16* orow = &ow[row * 72 + half * 32];
        u16* gp = &CTX[(size_t)(b*S + qbase + qg*32 + row) * D + h*DH + half * 32];
        #pragma unroll
        for (int i = 0; i < 4; ++i)
            *(bf16x8*)(gp + i * 8) = *(const bf16x8*)(orow + i * 8);
    }
}

extern "C" void kernel_launch(void* const* d_in, const int* in_sizes, int n_in,
                              void* d_out, int out_size, void* d_ws, size_t ws_size,
                              hipStream_t stream)
{
    const float* x    = (const float*)d_in[0];
    const float* cosT = (const float*)d_in[1];
    const float* sinT = (const float*)d_in[2];
    const float* wq   = (const float*)d_in[3];
    const float* wk   = (const float*)d_in[4];
    const float* wv   = (const float*)d_in[5];
    const float* wo   = (const float*)d_in[6];
    float* out = (float*)d_out;

    const size_t MD = (size_t)M_TOT * D;
    const size_t WD = (size_t)D * D;

    u16* xb   = (u16*)d_ws;
    u16* Qb   = xb + MD;
    u16* Kb   = Qb + MD;
    u16* Vb   = Kb + MD;
    u16* Vtb  = Vb + MD;
    u16* CTXb = Vtb + MD;
    u16* wqb  = CTXb + MD;
    u16* wkb  = wqb + WD;
    u16* wvb  = wkb + WD;
    u16* wob  = wvb + WD;

    // 1. fused bf16 casts (x + 4 weights in one launch)
    cvt_all_kernel<<<(int)((MD + 4*WD) / 8 / 256), 256, 0, stream>>>(
        x, wq, wk, wv, wo, xb, wqb, wkb, wvb, wob);

    // 2. fused QKV projections (z=0: Q rope+scale, z=1: K rope, z=2: V plain)
    gemm_mfma<1, 1><<<dim3(M_TOT / 128, D / 128, 3), 256, 0, stream>>>(
        xb, wqb, wkb, wvb, Qb, Kb, Vb, cosT, sinT);

    // 3. transpose V
    vtrans_kernel<<<dim3(S / 64, BH), 256, 0, stream>>>(Vb, Vtb);

    // 4. attention
    attn_mfma<<<dim3(M_TOT / QBLK * H), 256, 0, stream>>>(Qb, Kb, Vtb, CTXb);

    // 5. output projection (fp32 out)
    gemm_mfma<0, 0><<<dim3(M_TOT / 128, D / 128, 1), 256, 0, stream>>>(
        CTXb, wob, nullptr, nullptr, out, nullptr, nullptr, nullptr, nullptr);
}

// Round 9
// 185.608 us; speedup vs baseline: 1.2491x; 1.0912x over previous
//
#include <hip/hip_runtime.h>
#include <hip/hip_bf16.h>
#include <stdint.h>

#define B 4
#define S 2048
#define D 1024
#define H 16
#define DH 64
#define M_TOT (B*S)
#define BH (B*H)

typedef unsigned short u16;
typedef unsigned int u32;
typedef __attribute__((ext_vector_type(4))) float f32x4;
typedef __attribute__((ext_vector_type(16))) float f32x16;
typedef __attribute__((ext_vector_type(8))) short bf16x8;
typedef __attribute__((ext_vector_type(2))) unsigned int u32x2;

typedef const __attribute__((address_space(1))) unsigned int* gp_t;
typedef __attribute__((address_space(3))) unsigned int* lp_t;

__device__ __forceinline__ void gload_lds16(const void* g, void* l) {
    __builtin_amdgcn_global_load_lds((gp_t)g, (lp_t)l, 16, 0, 0);
}

__device__ __forceinline__ float bf2f(u16 u) {
    u32 t = ((u32)u) << 16;
    float f; __builtin_memcpy(&f, &t, 4); return f;
}
__device__ __forceinline__ u16 f2bf(float f) {   // RTNE
    u32 u; __builtin_memcpy(&u, &f, 4);
    u += 0x7fffu + ((u >> 16) & 1u);
    return (u16)(u >> 16);
}
__device__ __forceinline__ u32 packbf(float lo, float hi_) {
    __hip_bfloat162 h = __float22bfloat162_rn(float2{lo, hi_});
    u32 r; __builtin_memcpy(&r, &h, 4); return r;
}

__device__ __forceinline__ float exp2_fast(float x) { return __builtin_amdgcn_exp2f(x); }

#if __has_builtin(__builtin_amdgcn_permlane32_swap)
__device__ __forceinline__ void plswap(u32& a, u32& bb) {
    u32x2 r = __builtin_amdgcn_permlane32_swap(a, bb, false, false);
    a = r.x; bb = r.y;
}
#else
__device__ __forceinline__ void plswap(u32& a, u32& bb) {
    int hi = (threadIdx.x >> 5) & 1;
    u32 ra = (u32)__shfl_xor((int)a, 32);
    u32 rb = (u32)__shfl_xor((int)bb, 32);
    u32 na = hi ? rb : a;
    u32 nb = hi ? bb : ra;
    a = na; bb = nb;
}
#endif

// ---------------- fused fp32 -> bf16 cast for x + 4 weights ----------------
__global__ __launch_bounds__(256)
void cvt_all_kernel(const float* __restrict__ x,
                    const float* __restrict__ wq, const float* __restrict__ wk,
                    const float* __restrict__ wv, const float* __restrict__ wo,
                    u16* __restrict__ xb, u16* __restrict__ wqb, u16* __restrict__ wkb,
                    u16* __restrict__ wvb, u16* __restrict__ wob)
{
    const size_t MD = (size_t)M_TOT * D;
    const size_t WD = (size_t)D * D;       // 2^20
    size_t i = ((size_t)blockIdx.x * 256 + threadIdx.x) * 8;
    const float* src; u16* dst; size_t off;
    if (i < MD) { src = x; dst = xb; off = i; }
    else {
        size_t j = i - MD;
        int wsel = (int)(j >> 20);
        off = j & (WD - 1);
        if      (wsel == 0) { src = wq; dst = wqb; }
        else if (wsel == 1) { src = wk; dst = wkb; }
        else if (wsel == 2) { src = wv; dst = wvb; }
        else                { src = wo; dst = wob; }
    }
    float4 a = *(const float4*)(src + off);
    float4 b = *(const float4*)(src + off + 4);
    union { u16 u[8]; bf16x8 v; } o;
    o.u[0] = f2bf(a.x); o.u[1] = f2bf(a.y); o.u[2] = f2bf(a.z); o.u[3] = f2bf(a.w);
    o.u[4] = f2bf(b.x); o.u[5] = f2bf(b.y); o.u[6] = f2bf(b.z); o.u[7] = f2bf(b.w);
    *(bf16x8*)(dst + off) = o.v;
}

// ---------------- bf16 MFMA GEMM (m97 structure) ----------------
// QKV mode (DO_ROPE=1): z=0 -> Q rope + cs2 scale; z=1 -> K rope;
// z=2 -> V written TRANSPOSED into Vt[(b*16+h)*64+dh][s] (vtrans fused).
template<int WRITE_BF16, int DO_ROPE>
__global__ __launch_bounds__(256)
void gemm_mfma(const u16* __restrict__ X,
               const u16* __restrict__ W0, const u16* __restrict__ W1, const u16* __restrict__ W2,
               void* Y0, void* Y1, void* Y2,
               const float* __restrict__ cosT, const float* __restrict__ sinT)
{
    __shared__ __align__(16) u16 Al[128 * 32];
    __shared__ __align__(16) u16 Bl[128 * 32];

    const u16* Wm = (blockIdx.z == 0) ? W0 : (blockIdx.z == 1) ? W1 : W2;
    void* Yv      = (blockIdx.z == 0) ? Y0 : (blockIdx.z == 1) ? Y1 : Y2;

    const int t = threadIdx.x;
    const int w = t >> 6, ll = t & 63;
    const int wr = w >> 1, wc = w & 1;
    const int g = ll >> 4, lc = ll & 15;
    const int m0 = blockIdx.x * 128, n0 = blockIdx.y * 128;

    const int srow = t >> 2;
    const int scol = (t & 3) * 8;

    const u16* Xa = X + (size_t)m0 * D;
    const u16* Wa = Wm + (size_t)n0 * D;

    f32x4 acc[4][4];
    #pragma unroll
    for (int i = 0; i < 4; ++i)
        #pragma unroll
        for (int j = 0; j < 4; ++j)
            acc[i][j] = (f32x4){0.f, 0.f, 0.f, 0.f};

    for (int k0 = 0; k0 < D; k0 += 32) {
        gload_lds16(Xa + (size_t)(srow)      * D + k0 + scol, &Al[(w * 64) * 8]);
        gload_lds16(Xa + (size_t)(64 + srow) * D + k0 + scol, &Al[(256 + w * 64) * 8]);
        gload_lds16(Wa + (size_t)(srow)      * D + k0 + scol, &Bl[(w * 64) * 8]);
        gload_lds16(Wa + (size_t)(64 + srow) * D + k0 + scol, &Bl[(256 + w * 64) * 8]);
        __syncthreads();

        bf16x8 af[4], bf[4];
        #pragma unroll
        for (int i = 0; i < 4; ++i)
            af[i] = *(const bf16x8*)&Al[(wr * 64 + i * 16 + lc) * 32 + g * 8];
        #pragma unroll
        for (int j = 0; j < 4; ++j)
            bf[j] = *(const bf16x8*)&Bl[(wc * 64 + j * 16 + lc) * 32 + g * 8];

        #pragma unroll
        for (int i = 0; i < 4; ++i)
            #pragma unroll
            for (int j = 0; j < 4; ++j)
                acc[i][j] = __builtin_amdgcn_mfma_f32_16x16x32_bf16(af[i], bf[j], acc[i][j], 0, 0, 0);
        __syncthreads();
    }

    if (DO_ROPE && blockIdx.z < 2) {
        const float scale = (blockIdx.z == 0) ? (0.125f * 1.44269504f) : 1.0f;
        u16* Y = (u16*)Yv;
        #pragma unroll
        for (int i = 0; i < 4; ++i)
            #pragma unroll
            for (int r = 0; r < 4; ++r) {
                int row = m0 + wr * 64 + i * 16 + g * 4 + r;
                int s = row & (S - 1);
                #pragma unroll
                for (int jh = 0; jh < 2; ++jh) {
                    float c  = cosT[s * DH + jh * 16 + lc];
                    float sn = sinT[s * DH + jh * 16 + lc];
                    float a0 = acc[i][jh][r], a1 = acc[i][jh + 2][r];
                    size_t base = (size_t)row * D + n0 + wc * 64;
                    Y[base + jh * 16 + lc]       = f2bf((a0 * c - a1 * sn) * scale);
                    Y[base + (jh + 2) * 16 + lc] = f2bf((a1 * c + a0 * sn) * scale);
                }
            }
    } else if (DO_ROPE) {
        // z==2: V projection, write transposed: Vt[(b*16 + col/64)*64 + col%64][s]
        u16* Y = (u16*)Yv;
        #pragma unroll
        for (int i = 0; i < 4; ++i)
            #pragma unroll
            for (int j = 0; j < 4; ++j) {
                int row = m0 + wr * 64 + i * 16 + g * 4;       // token index (r=0)
                int col = n0 + wc * 64 + j * 16 + lc;          // feature index
                int bt = row >> 11, s = row & (S - 1);
                size_t vtrow = (size_t)(bt * 16 + (col >> 6)) * 64 + (col & 63);
                u32 w0 = packbf(acc[i][j][0], acc[i][j][1]);
                u32 w1 = packbf(acc[i][j][2], acc[i][j][3]);
                u32x2 pr; pr.x = w0; pr.y = w1;
                *(u32x2*)&Y[vtrow * S + s] = pr;               // 4 consecutive s, 8B store
            }
    } else if (WRITE_BF16) {
        u16* Y = (u16*)Yv;
        #pragma unroll
        for (int i = 0; i < 4; ++i)
            #pragma unroll
            for (int j = 0; j < 4; ++j)
                #pragma unroll
                for (int r = 0; r < 4; ++r) {
                    int row = m0 + wr * 64 + i * 16 + g * 4 + r;
                    int col = n0 + wc * 64 + j * 16 + lc;
                    Y[(size_t)row * D + col] = f2bf(acc[i][j][r]);
                }
    } else {
        float* Y = (float*)Yv;
        #pragma unroll
        for (int i = 0; i < 4; ++i)
            #pragma unroll
            for (int j = 0; j < 4; ++j)
                #pragma unroll
                for (int r = 0; r < 4; ++r) {
                    int row = m0 + wr * 64 + i * 16 + g * 4 + r;
                    int col = n0 + wc * 64 + j * 16 + lc;
                    Y[(size_t)row * D + col] = acc[i][j][r];
                }
    }
}

// ---------------- MFMA flash attention: 128-key tiles, 4 chunk passes ------
// KVT=128 halves barrier count vs 64. Per tile: 4 serial 32-key chunks
// (QK -> exp/pack -> lsum+PV), double-buffered 32KB K+V staging.
// K tile [128 keys][64 dh] rows 128B, swizzle (row&7)<<4 (unchanged).
// V tile [64 dh][128 keys] rows 256B, swizzle (row&15)<<4 (write+read pair).
#define QBLK 256
#define KVT 128
#define NT (S / KVT)

__global__ __launch_bounds__(256, 2)
void attn_mfma(const u16* __restrict__ Q, const u16* __restrict__ Kg,
               const u16* __restrict__ Vt, u16* __restrict__ CTX)
{
    __shared__ __align__(16) u16 smem[32768];   // 2 x (K 16KB + V 16KB)

    const int t  = threadIdx.x;
    const int w  = t >> 6;
    const int q  = t & 31;
    const int hi = (t >> 5) & 1;

    // XCD-chunked swizzle: 8 bh per XCD
    const int bid  = blockIdx.x;          // 0..511
    const int xcd  = bid & 7;
    const int slot = bid >> 3;            // 0..63
    const int bh   = xcd * 8 + (slot >> 3);
    const int qb   = slot & 7;
    const int b = bh >> 4, h = bh & 15;
    const int q0 = qb * QBLK;
    const int qbase = q0 + w * 64;

    // Q as B-fragments for 2 q-groups
    bf16x8 qf[2][4];
    #pragma unroll
    for (int qg = 0; qg < 2; ++qg) {
        const u16* qp = &Q[(size_t)(b*S + qbase + qg*32 + q) * D + h*DH + hi*8];
        qf[qg][0] = *(const bf16x8*)(qp);
        qf[qg][1] = *(const bf16x8*)(qp + 16);
        qf[qg][2] = *(const bf16x8*)(qp + 32);
        qf[qg][3] = *(const bf16x8*)(qp + 48);
    }

    bf16x8 ones;
    {
        union { u16 u[8]; bf16x8 v; } ou;
        #pragma unroll
        for (int i = 0; i < 8; ++i) ou.u[i] = 0x3f80;   // bf16 1.0
        ones = ou.v;
    }

    f32x16 po[4], lsum[2], zv;
    #pragma unroll
    for (int i = 0; i < 16; ++i) {
        po[0][i] = 0.f; po[1][i] = 0.f; po[2][i] = 0.f; po[3][i] = 0.f;
        lsum[0][i] = 0.f; lsum[1][i] = 0.f; zv[i] = 0.f;
    }

    // K staging geometry (128B rows): 8 lanes/row
    const int ksrow = t >> 3;                                 // 0..31
    const int kscol = (((t & 7) << 4) ^ ((ksrow & 7) << 4)) >> 1;
    // V staging geometry (256B rows): 16 lanes/row, pre-swizzled source col
    const int vsrow = t >> 4;                                 // 0..15
    const int vscol = (((t & 15) ^ (vsrow & 15)) << 3);       // u16 units
    const int rsw  = (q & 7) << 4;    // K read swizzle (bytes)
    const int vsw  = (q & 15) << 4;   // V read swizzle (bytes)

    u16* buf0 = smem;
    u16* buf1 = smem + 16384;

    const u16* kg = Kg + ((size_t)(b * S) + ksrow) * D + (size_t)h * DH + kscol;
    const u16* vg = Vt + ((size_t)bh * DH + vsrow) * S + vscol;

    #define STAGE(dst) do {                                         \
        gload_lds16(kg,           (dst) + 0*2048 + w*512);          \
        gload_lds16(kg + 32*D,    (dst) + 1*2048 + w*512);          \
        gload_lds16(kg + 64*D,    (dst) + 2*2048 + w*512);          \
        gload_lds16(kg + 96*D,    (dst) + 3*2048 + w*512);          \
        gload_lds16(vg,           (dst) + 8192 + 0*2048 + w*512);   \
        gload_lds16(vg + 16*S,    (dst) + 8192 + 1*2048 + w*512);   \
        gload_lds16(vg + 32*S,    (dst) + 8192 + 2*2048 + w*512);   \
        gload_lds16(vg + 48*S,    (dst) + 8192 + 3*2048 + w*512);   \
        kg += (size_t)KVT * D; vg += KVT; } while (0)

    auto compute = [&](const u16* base) {
        const u16* Kl = base;
        const u16* Vl = base + 8192;
        #pragma unroll
        for (int c = 0; c < 4; ++c) {
            // ---- QK for keys c*32 .. c*32+31 ----
            f32x16 p0, p1;
            {
                const u16* kr = &Kl[(c*32 + q) << 6];
                bf16x8 k0 = *(const bf16x8*)&kr[((0*32 + hi*16) ^ rsw) >> 1];
                __builtin_amdgcn_s_setprio(1);
                p0 = __builtin_amdgcn_mfma_f32_32x32x16_bf16(k0, qf[0][0], zv, 0, 0, 0);
                p1 = __builtin_amdgcn_mfma_f32_32x32x16_bf16(k0, qf[1][0], zv, 0, 0, 0);
                #pragma unroll
                for (int cc = 1; cc < 4; ++cc) {
                    bf16x8 kf = *(const bf16x8*)&kr[((cc*32 + hi*16) ^ rsw) >> 1];
                    p0 = __builtin_amdgcn_mfma_f32_32x32x16_bf16(kf, qf[0][cc], p0, 0, 0, 0);
                    p1 = __builtin_amdgcn_mfma_f32_32x32x16_bf16(kf, qf[1][cc], p1, 0, 0, 0);
                }
                __builtin_amdgcn_s_setprio(0);
            }

            // ---- P = exp2(score), pack to bf16 fragments ----
            u32 W0[8], W1[8];
            #pragma unroll
            for (int j = 0; j < 8; ++j) {
                W0[j] = packbf(exp2_fast(p0[2*j]), exp2_fast(p0[2*j + 1]));
                W1[j] = packbf(exp2_fast(p1[2*j]), exp2_fast(p1[2*j + 1]));
            }
            plswap(W0[0], W0[2]); plswap(W0[1], W0[3]);
            plswap(W0[4], W0[6]); plswap(W0[5], W0[7]);
            plswap(W1[0], W1[2]); plswap(W1[1], W1[3]);
            plswap(W1[4], W1[6]); plswap(W1[5], W1[7]);
            bf16x8 pa0a, pa0b, pa1a, pa1b;
            {
                union { u32 u[4]; bf16x8 v; } pb;
                pb.u[0]=W0[0]; pb.u[1]=W0[1]; pb.u[2]=W0[2]; pb.u[3]=W0[3]; pa0a = pb.v;
                pb.u[0]=W0[4]; pb.u[1]=W0[5]; pb.u[2]=W0[6]; pb.u[3]=W0[7]; pa0b = pb.v;
                pb.u[0]=W1[0]; pb.u[1]=W1[1]; pb.u[2]=W1[2]; pb.u[3]=W1[3]; pa1a = pb.v;
                pb.u[0]=W1[4]; pb.u[1]=W1[5]; pb.u[2]=W1[6]; pb.u[3]=W1[7]; pa1b = pb.v;
            }

            // ---- lsum += ones^T x P ; po += Vt_frag x pa ----
            __builtin_amdgcn_s_setprio(1);
            lsum[0] = __builtin_amdgcn_mfma_f32_32x32x16_bf16(ones, pa0a, lsum[0], 0, 0, 0);
            lsum[1] = __builtin_amdgcn_mfma_f32_32x32x16_bf16(ones, pa1a, lsum[1], 0, 0, 0);
            lsum[0] = __builtin_amdgcn_mfma_f32_32x32x16_bf16(ones, pa0b, lsum[0], 0, 0, 0);
            lsum[1] = __builtin_amdgcn_mfma_f32_32x32x16_bf16(ones, pa1b, lsum[1], 0, 0, 0);
            #pragma unroll
            for (int kk = 0; kk < 2; ++kk) {
                int vb = ((c*64 + kk*32 + hi*16) ^ vsw) >> 1;
                bf16x8 v0 = *(const bf16x8*)&Vl[(q << 7) + vb];
                bf16x8 v1 = *(const bf16x8*)&Vl[((32 + q) << 7) + vb];
                bf16x8 pq0 = kk ? pa0b : pa0a;
                bf16x8 pq1 = kk ? pa1b : pa1a;
                po[0] = __builtin_amdgcn_mfma_f32_32x32x16_bf16(v0, pq0, po[0], 0, 0, 0);
                po[1] = __builtin_amdgcn_mfma_f32_32x32x16_bf16(v1, pq0, po[1], 0, 0, 0);
                po[2] = __builtin_amdgcn_mfma_f32_32x32x16_bf16(v0, pq1, po[2], 0, 0, 0);
                po[3] = __builtin_amdgcn_mfma_f32_32x32x16_bf16(v1, pq1, po[3], 0, 0, 0);
            }
            __builtin_amdgcn_s_setprio(0);
        }
    };

    // prologue: stage tile 0
    STAGE(buf0);
    asm volatile("s_waitcnt vmcnt(0)" ::: "memory");
    __builtin_amdgcn_s_barrier();

    for (int ti = 0; ti < NT; ti += 2) {
        STAGE(buf1);                       // tile ti+1
        compute(buf0);                     // tile ti
        asm volatile("s_waitcnt vmcnt(0)" ::: "memory");
        __builtin_amdgcn_s_barrier();
        if (ti < NT - 2) STAGE(buf0);      // tile ti+2
        compute(buf1);                     // tile ti+1
        asm volatile("s_waitcnt vmcnt(0)" ::: "memory");
        __builtin_amdgcn_s_barrier();
    }
    #undef STAGE

    // ---- epilogue: per q-group normalize + transpose via wave-local LDS ----
    u16* ow = &smem[w * 2304];   // 32 rows x 72 u16 per wave (wave-local)
    #pragma unroll
    for (int qg = 0; qg < 2; ++qg) {
        float inv = 1.f / lsum[qg][0];
        #pragma unroll
        for (int r = 0; r < 16; ++r) {
            int d0 = (r & 3) + 8 * (r >> 2) + 4 * hi;
            ow[q * 72 + d0]      = f2bf(po[qg*2 + 0][r] * inv);
            ow[q * 72 + 32 + d0] = f2bf(po[qg*2 + 1][r] * inv);
        }
        int row = (t & 63) >> 1, half = t & 1;
        const u16* orow = &ow[row * 72 + half * 32];
        u16* gp = &CTX[(size_t)(b*S + qbase + qg*32 + row) * D + h*DH + half * 32];
        #pragma unroll
        for (int i = 0; i < 4; ++i)
            *(bf16x8*)(gp + i * 8) = *(const bf16x8*)(orow + i * 8);
    }
}

extern "C" void kernel_launch(void* const* d_in, const int* in_sizes, int n_in,
                              void* d_out, int out_size, void* d_ws, size_t ws_size,
                              hipStream_t stream)
{
    const float* x    = (const float*)d_in[0];
    const float* cosT = (const float*)d_in[1];
    const float* sinT = (const float*)d_in[2];
    const float* wq   = (const float*)d_in[3];
    const float* wk   = (const float*)d_in[4];
    const float* wv   = (const float*)d_in[5];
    const float* wo   = (const float*)d_in[6];
    float* out = (float*)d_out;

    const size_t MD = (size_t)M_TOT * D;
    const size_t WD = (size_t)D * D;

    u16* xb   = (u16*)d_ws;
    u16* Qb   = xb + MD;
    u16* Kb   = Qb + MD;
    u16* Vtb  = Kb + MD;
    u16* CTXb = Vtb + MD;
    u16* wqb  = CTXb + MD;
    u16* wkb  = wqb + WD;
    u16* wvb  = wkb + WD;
    u16* wob  = wvb + WD;

    // 1. fused bf16 casts (x + 4 weights in one launch)
    cvt_all_kernel<<<(int)((MD + 4*WD) / 8 / 256), 256, 0, stream>>>(
        x, wq, wk, wv, wo, xb, wqb, wkb, wvb, wob);

    // 2. fused QKV projections (z=0: Q rope+scale, z=1: K rope, z=2: V -> Vt transposed)
    gemm_mfma<1, 1><<<dim3(M_TOT / 128, D / 128, 3), 256, 0, stream>>>(
        xb, wqb, wkb, wvb, Qb, Kb, Vtb, cosT, sinT);

    // 3. attention
    attn_mfma<<<dim3(M_TOT / QBLK * H), 256, 0, stream>>>(Qb, Kb, Vtb, CTXb);

    // 4. output projection (fp32 out)
    gemm_mfma<0, 0><<<dim3(M_TOT / 128, D / 128, 1), 256, 0, stream>>>(
        CTXb, wob, nullptr, nullptr, out, nullptr, nullptr, nullptr, nullptr);
}